// Round 2
// baseline (1454.905 us; speedup 1.0000x reference)
//
#include <hip/hip_runtime.h>
#include <hip/hip_bf16.h>
#include <math.h>

constexpr int BATCH  = 65536;
constexpr int IN_DIM = 512;
constexpr int LATENT = 32;
constexpr int NTRIL  = 528;        // 32*33/2
constexpr float BN_EPS = 1e-5f;
constexpr float SLOPE  = 0.01f;

// ---- kernel A (encoder + mu) config ----
constexpr int A_RPB = 64;          // batch rows per block
constexpr int HSTR  = 36;          // h_sh row stride (16B aligned, breaks pow2)

// ---- kernel B (elts + cov) config ----
constexpr int B_RPB     = 8;       // batch rows per block
constexpr int B_THREADS = 128;     // 2 waves
constexpr int LSTR = 36;           // floats per L row (8 quads + 1 pad quad)
constexpr int LROW = LATENT * LSTR; // 1152 floats per batch row

__device__ __forceinline__ float leaky(float v) {
    return v >= 0.0f ? v : SLOPE * v;
}

// ============================ Kernel A: h + mus ============================
__global__ __launch_bounds__(256)
void pm_enc(const float* __restrict__ x,
            const float* __restrict__ W_enc,
            const float* __restrict__ b_enc,
            const float* __restrict__ bn_gamma,
            const float* __restrict__ bn_beta,
            const float* __restrict__ bn_mean,
            const float* __restrict__ bn_var,
            const float* __restrict__ W_mu,
            const float* __restrict__ b_mu,
            float* __restrict__ h_out,
            float* __restrict__ mu_out)
{
    __shared__ __align__(16) float h_sh[A_RPB][HSTR];   // 9216 B

    const int t = threadIdx.x;
    const int row0 = blockIdx.x * A_RPB;
    const int c = t & 31;          // latent column
    const int g = t >> 5;          // 0..7 -> rows g*8 .. g*8+7

    // ---------------- h = leaky(BN(x @ W_enc + b_enc)) ----------------
    {
        const float4* __restrict__ xp =
            (const float4*)(x + (size_t)(row0 + g * 8) * IN_DIM);
        const float* __restrict__ Wc = W_enc + c;

        float acc[8];
        #pragma unroll
        for (int j = 0; j < 8; ++j) acc[j] = 0.0f;

        #pragma unroll 2
        for (int k4 = 0; k4 < IN_DIM / 4; ++k4) {
            const float w0 = Wc[(4 * k4 + 0) * LATENT];
            const float w1 = Wc[(4 * k4 + 1) * LATENT];
            const float w2 = Wc[(4 * k4 + 2) * LATENT];
            const float w3 = Wc[(4 * k4 + 3) * LATENT];
            #pragma unroll
            for (int j = 0; j < 8; ++j) {
                const float4 xv = xp[j * (IN_DIM / 4) + k4];
                acc[j] += xv.x * w0 + xv.y * w1 + xv.z * w2 + xv.w * w3;
            }
        }

        const float be = b_enc[c];
        const float gm = bn_gamma[c];
        const float bt = bn_beta[c];
        const float mn = bn_mean[c];
        const float iv = rsqrtf(bn_var[c] + BN_EPS);

        #pragma unroll
        for (int j = 0; j < 8; ++j) {
            float v = acc[j] + be;
            v = gm * (v - mn) * iv + bt;
            v = leaky(v);
            const int r = g * 8 + j;
            h_sh[r][c] = v;
            h_out[(size_t)(row0 + r) * LATENT + c] = v;
        }
    }
    __syncthreads();

    // ---------------- mus = leaky(h @ W_mu + b_mu) ----------------
    {
        float wmu[LATENT];
        #pragma unroll
        for (int k = 0; k < LATENT; ++k) wmu[k] = W_mu[k * LATENT + c];
        const float bm = b_mu[c];
        #pragma unroll
        for (int j = 0; j < 8; ++j) {
            const int r = g * 8 + j;
            const float4* __restrict__ hr = (const float4*)&h_sh[r][0];
            float a = bm;
            #pragma unroll
            for (int k4 = 0; k4 < 8; ++k4) {
                const float4 hv = hr[k4];
                a += hv.x * wmu[4*k4+0] + hv.y * wmu[4*k4+1]
                   + hv.z * wmu[4*k4+2] + hv.w * wmu[4*k4+3];
            }
            mu_out[(size_t)(row0 + r) * LATENT + c] = leaky(a);
        }
    }
}

// ============================ Kernel B: L + cov ============================
typedef __attribute__((ext_vector_type(8)))  short bf16x8;
typedef __attribute__((ext_vector_type(16))) float f32x16;

union FragU { unsigned u[4]; bf16x8 v; };

// pack 2 floats to bf16x2 bits (RTN), also return the bf16-rounded-back floats
__device__ __forceinline__ unsigned cvt2(float a, float b, float& backa, float& backb) {
    __hip_bfloat162 h = __float22bfloat162_rn(make_float2(a, b));
    float2 bk = __bfloat1622float2(h);
    backa = bk.x; backb = bk.y;
    unsigned u; __builtin_memcpy(&u, &h, 4);
    return u;
}
__device__ __forceinline__ unsigned pk2(float a, float b) {
    __hip_bfloat162 h = __float22bfloat162_rn(make_float2(a, b));
    unsigned u; __builtin_memcpy(&u, &h, 4);
    return u;
}

__global__ __launch_bounds__(B_THREADS)
void pm_cov(const float* __restrict__ h_glob,
            const float* __restrict__ W_ch,
            const float* __restrict__ b_ch,
            float* __restrict__ cov_out)
{
    // L layout: [local batch row][32 L-rows x LSTR floats], quad-swizzled:
    // logical (ri, quad q) stored at ri*LSTR + ((q ^ (ri>>2))<<2)
    __shared__ __align__(16) float L_sh[B_RPB * LROW];  // 36864 B
    __shared__ __align__(16) float h_sh[B_RPB * LATENT]; // 1024 B

    const int t = threadIdx.x;
    const int row0 = blockIdx.x * B_RPB;

    // ---- zero-fill L (upper triangle must be exactly 0 for the MFMA) ----
    {
        float4* z = (float4*)L_sh;
        #pragma unroll
        for (int i = 0; i < (B_RPB * LROW / 4) / B_THREADS; ++i)
            z[t + i * B_THREADS] = make_float4(0.f, 0.f, 0.f, 0.f);
    }
    // ---- stage h (8 rows x 32) ----
    {
        const float* hg = h_glob + (size_t)row0 * LATENT;
        h_sh[t]       = hg[t];
        h_sh[t + 128] = hg[t + 128];
    }
    __syncthreads();

    // ---- 3a: elts = leaky(h @ W_ch + b_ch), diag softplus-clip, scatter to L_sh ----
    #pragma unroll 1
    for (int q = t; q < NTRIL / 4; q += B_THREADS) {   // 132 j-quads
        const int j0 = 4 * q;
        float4 a[8];
        {
            const float4 bb = *(const float4*)(b_ch + j0);
            #pragma unroll
            for (int r = 0; r < 8; ++r) a[r] = bb;
        }
        #pragma unroll
        for (int kq = 0; kq < 8; ++kq) {
            float4 w[4];
            #pragma unroll
            for (int e = 0; e < 4; ++e)
                w[e] = *(const float4*)(W_ch + (size_t)(4 * kq + e) * NTRIL + j0);
            #pragma unroll
            for (int r = 0; r < 8; ++r) {
                const float4 hv = *(const float4*)&h_sh[r * LATENT + 4 * kq];
                a[r].x += hv.x*w[0].x + hv.y*w[1].x + hv.z*w[2].x + hv.w*w[3].x;
                a[r].y += hv.x*w[0].y + hv.y*w[1].y + hv.z*w[2].y + hv.w*w[3].y;
                a[r].z += hv.x*w[0].z + hv.y*w[1].z + hv.z*w[2].z + hv.w*w[3].z;
                a[r].w += hv.x*w[0].w + hv.y*w[1].w + hv.z*w[2].w + hv.w*w[3].w;
            }
        }
        #pragma unroll
        for (int e = 0; e < 4; ++e) {
            const int j = j0 + e;
            int ri = (int)((sqrtf(8.0f * (float)j + 1.0f) - 1.0f) * 0.5f);
            if ((ri + 1) * (ri + 2) / 2 <= j) ++ri;
            if (ri * (ri + 1) / 2 > j) --ri;
            const int ci = j - ri * (ri + 1) / 2;
            const bool isdiag = (ci == ri);
            const int addr = ri * LSTR + ((((ci >> 2) ^ (ri >> 2))) << 2) + (ci & 3);
            #pragma unroll
            for (int r = 0; r < 8; ++r) {
                float v = (e == 0) ? a[r].x : (e == 1) ? a[r].y
                        : (e == 2) ? a[r].z : a[r].w;
                v = leaky(v);
                if (isdiag) {
                    float sp = v > 20.0f ? v : log1pf(__expf(v));
                    v = fminf(fmaxf(sp, 0.001f), 100.0f) + 0.01f;
                }
                L_sh[r * LROW + addr] = v;
            }
        }
    }
    __syncthreads();

    // ---- 3b: cov = L L^T + 0.01 I  via bf16-split MFMA ----
    // wave w handles local rows 4w..4w+3; lane: m = l&31 (L row), kh = l>>5 (k half)
    {
        const int wave = t >> 6;
        const int l    = t & 63;
        const int m    = l & 31;
        const int kh   = l >> 5;

        #pragma unroll 1
        for (int i = 0; i < 4; ++i) {
            const int lrow = wave * 4 + i;
            const float* Lr = L_sh + lrow * LROW + m * LSTR;

            f32x16 acc = {};
            #pragma unroll
            for (int s = 0; s < 2; ++s) {           // two K=16 steps cover K=32
                const int q0 = 4 * s + 2 * kh;      // this lane's first logical quad
                const float4 f0 = *(const float4*)(Lr + (((q0    ) ^ (m >> 2)) << 2));
                const float4 f1 = *(const float4*)(Lr + (((q0 + 1) ^ (m >> 2)) << 2));

                float b0, b1, b2, b3, b4, b5, b6, b7;
                FragU hi, lo;
                hi.u[0] = cvt2(f0.x, f0.y, b0, b1);
                hi.u[1] = cvt2(f0.z, f0.w, b2, b3);
                hi.u[2] = cvt2(f1.x, f1.y, b4, b5);
                hi.u[3] = cvt2(f1.z, f1.w, b6, b7);
                lo.u[0] = pk2(f0.x - b0, f0.y - b1);
                lo.u[1] = pk2(f0.z - b2, f0.w - b3);
                lo.u[2] = pk2(f1.x - b4, f1.y - b5);
                lo.u[3] = pk2(f1.z - b6, f1.w - b7);

                acc = __builtin_amdgcn_mfma_f32_32x32x16_bf16(hi.v, hi.v, acc, 0, 0, 0);
                acc = __builtin_amdgcn_mfma_f32_32x32x16_bf16(hi.v, lo.v, acc, 0, 0, 0);
                acc = __builtin_amdgcn_mfma_f32_32x32x16_bf16(lo.v, hi.v, acc, 0, 0, 0);
            }

            // C/D layout (m101): col = lane&31, row = (reg&3) + 8*(reg>>2) + 4*(lane>>5)
            float* crow = cov_out + (size_t)(row0 + lrow) * (LATENT * LATENT);
            #pragma unroll
            for (int n = 0; n < 16; ++n) {
                const int R = (n & 3) + 8 * (n >> 2) + 4 * kh;
                float v = acc[n];
                if (R == m) v += 0.01f;
                crow[R * LATENT + m] = v;
            }
        }
    }
}

extern "C" void kernel_launch(void* const* d_in, const int* in_sizes, int n_in,
                              void* d_out, int out_size, void* d_ws, size_t ws_size,
                              hipStream_t stream) {
    const float* x        = (const float*)d_in[0];
    const float* W_enc    = (const float*)d_in[1];
    const float* b_enc    = (const float*)d_in[2];
    const float* bn_gamma = (const float*)d_in[3];
    const float* bn_beta  = (const float*)d_in[4];
    const float* bn_mean  = (const float*)d_in[5];
    const float* bn_var   = (const float*)d_in[6];
    const float* W_mu     = (const float*)d_in[7];
    const float* b_mu     = (const float*)d_in[8];
    const float* W_ch     = (const float*)d_in[9];
    const float* b_ch     = (const float*)d_in[10];
    float* out = (float*)d_out;

    float* h_out   = out;
    float* mu_out  = out + (size_t)BATCH * LATENT;
    float* cov_out = out + (size_t)2 * BATCH * LATENT;

    pm_enc<<<dim3(BATCH / A_RPB), dim3(256), 0, stream>>>(
        x, W_enc, b_enc, bn_gamma, bn_beta, bn_mean, bn_var,
        W_mu, b_mu, h_out, mu_out);

    pm_cov<<<dim3(BATCH / B_RPB), dim3(B_THREADS), 0, stream>>>(
        h_out, W_ch, b_ch, cov_out);
}